// Round 8
// baseline (57598.163 us; speedup 1.0000x reference)
//
#include <hip/hip_runtime.h>

#define Bsz  4
#define Lsz  4096
#define Csz  1024
#define NHsz 16
#define CSsz 16
#define HFsz 64
#define HF4sz 256
#define NCsz 256

// ---------------------------------------------------------------------------
// fp32 GEMM: C[M,N] = A[M,K] @ B[K,N].  64x64 tile, BK=16, 4x4 microtile.
// (unchanged)
// ---------------------------------------------------------------------------
__global__ __launch_bounds__(256)
void gemm64(const float* __restrict__ A, const float* __restrict__ Bm,
            float* __restrict__ Cm, int M, int N, int K)
{
  __shared__ __attribute__((aligned(16))) float As[16][68];
  __shared__ __attribute__((aligned(16))) float Bs[16][64];
  const int t  = threadIdx.x;
  const int tx = t & 15, ty = t >> 4;
  const int row0 = blockIdx.y * 64, col0 = blockIdx.x * 64;
  const int ar = t >> 2, ak = (t & 3) * 4;
  const int bk = t >> 4, bc = (t & 15) * 4;
  float acc[4][4] = {};

  for (int k0 = 0; k0 < K; k0 += 16) {
    float4 a4 = *(const float4*)&A[(size_t)(row0 + ar) * K + k0 + ak];
    float4 b4 = *(const float4*)&Bm[(size_t)(k0 + bk) * N + col0 + bc];
    As[ak + 0][ar] = a4.x; As[ak + 1][ar] = a4.y;
    As[ak + 2][ar] = a4.z; As[ak + 3][ar] = a4.w;
    *(float4*)&Bs[bk][bc] = b4;
    __syncthreads();
#pragma unroll
    for (int kk = 0; kk < 16; ++kk) {
      float4 av = *(const float4*)&As[kk][ty * 4];
      float4 bv = *(const float4*)&Bs[kk][tx * 4];
      acc[0][0] += av.x * bv.x; acc[0][1] += av.x * bv.y;
      acc[0][2] += av.x * bv.z; acc[0][3] += av.x * bv.w;
      acc[1][0] += av.y * bv.x; acc[1][1] += av.y * bv.y;
      acc[1][2] += av.y * bv.z; acc[1][3] += av.y * bv.w;
      acc[2][0] += av.z * bv.x; acc[2][1] += av.z * bv.y;
      acc[2][2] += av.z * bv.z; acc[2][3] += av.z * bv.w;
      acc[3][0] += av.w * bv.x; acc[3][1] += av.w * bv.y;
      acc[3][2] += av.w * bv.z; acc[3][3] += av.w * bv.w;
    }
    __syncthreads();
  }
#pragma unroll
  for (int r = 0; r < 4; ++r) {
    float4 v = make_float4(acc[r][0], acc[r][1], acc[r][2], acc[r][3]);
    *(float4*)&Cm[(size_t)(row0 + ty * 4 + r) * N + col0 + tx * 4] = v;
  }
}

// ---------------------------------------------------------------------------
// ilr -> coeff table (unchanged)
// ---------------------------------------------------------------------------
__global__ __launch_bounds__(256)
void ilr_coeff(const float* __restrict__ H, const float* __restrict__ Wil,
               const float* __restrict__ bil, float* __restrict__ coeff)
{
  __shared__ float sRow[4][1024];
  __shared__ float sP[4][16][17];
  const int t = threadIdx.x;
  const size_t r0 = (size_t)blockIdx.x * 4;
  for (int rr = 0; rr < 4; ++rr)
    for (int c = t; c < 1024; c += 256)
      sRow[rr][c] = H[(r0 + rr) * 1024 + c];
  __syncthreads();
  const int hh = t & 15, sl = t >> 4;
  for (int rr = 0; rr < 4; ++rr) {
    float acc = 0.f;
    for (int kk = 0; kk < 64; ++kk)
      acc += sRow[rr][sl * 64 + kk] * Wil[(sl * 64 + kk) * 16 + hh];
    sP[rr][sl][hh] = acc;
  }
  __syncthreads();
  if (t < 64) {
    const int rr = t >> 4, h2 = t & 15;
    float s = 0.f;
    for (int sl2 = 0; sl2 < 16; ++sl2) s += sP[rr][sl2][h2];
    s += bil[h2];
    const float sig = 1.f / (1.f + expf(-s));
    const int r  = (int)(r0 + rr);
    const int b  = r >> 12, l = r & 4095, nc = l >> 4, cs = l & 15;
    coeff[((b * 16 + h2) * NCsz + nc) * CSsz + cs] = sig / ((float)(cs + 1) * 64.0f);
  }
}

// ---------------------------------------------------------------------------
// TTT scan v9: 512 threads, UNIFORM work split (no A/B wave specialization).
//
// Round-7 post-mortem: 1024-thr blocks have an immovable 64-VGPR cap ->
// v8 spilled in hot loops (5.4GB scratch writes) + stride-256 repack
// (64M bank conflicts).  512-thr blocks get 128 VGPRs and ran spill-free
// (v5, 9.0ms).  v5's residual waste: specialized phases idle one of the
// two waves/SIMD (P1 imbalance, P4/P5/P7 one-sided).
//
// v9: every thread holds W1 half-col (32) + W2 col-slice (32) + W2 row-half
// (32) = 96 persistent regs; same total state as v5, half per thread.
// EVERY phase runs on all 512 threads with balanced work:
//   P1  : Z1 + z1bp K-half partials (kh=t>>8); kh0->sZ1, kh1->sZ1b(tmp);
//         z1bp: kh0 exports to sPg, kh1 keeps in regs
//   P1.5: sZ1 += sZ1b reduce (all); kh1 combines z1bp (keeps rows 8-16,
//         stores rows 0-8); kh0 (256 thr) computes Attn1 from global
//   P2  : Z2 partials, role (qq,m), 8 slices -> sP
//   P3  : g2 = reduce(sP) - XA -> sg2 (all); kh0 reads back z1bp finals
//   P4  : g1 mm-half partials -> sPg + fused w2row-half update (i-outer,
//         scalar s, no s[16] array)
//   P5  : Z1b rows [kh*8,+8) finalize -> sZ1b (all; tril per row)
//   P6  : W1 half-update (first: frees g1v) | Z2b partials -> sP |
//         w2col-slice update | Attn2 K-half -> sA2p
//   P7  : Z2b reduce + Attn2 combine + store, 2 rows/thread (no trailing
//         barrier: reads sP/sA2p/sg2/sCoBuf[cur], disjoint from next P1)
// LDS ~104KB -> 1 WG/CU.  7 barriers/chunk.  Peak live regs ~120 < 128.
// ---------------------------------------------------------------------------
__global__ __launch_bounds__(512)
void ttt_scan(const float* __restrict__ XA, const float* __restrict__ XBuf,
              const float* __restrict__ XCbuf, const float* __restrict__ coeff,
              const float* __restrict__ W1g, const float* __restrict__ W2g,
              float* __restrict__ Out)
{
  __shared__ __attribute__((aligned(16))) float sZ1 [16 * 260]; // Z1 (P1: lo-part)
  __shared__ __attribute__((aligned(16))) float sZ1b[16 * 260]; // P1: hi-part; P5+: Z1b
  __shared__ __attribute__((aligned(16))) float sg2 [16 * 68];
  __shared__ __attribute__((aligned(16))) float sP  [8 * 16 * 64];  // 32K partials
  __shared__ __attribute__((aligned(16))) float sPg [2 * 16 * 256]; // 32K g1 partials | z1bp staging
  __shared__ float sA1 [16 * 17];
  __shared__ float sA2p[2 * 16 * 17];
  __shared__ float sCoBuf[2 * 16];

  const int t   = threadIdx.x;
  const int bh  = blockIdx.x;             // 0..63
  const int b   = bh >> 4, h = bh & 15;
  const int n   = t & 255;                // W1 col / W2 row
  const int kh  = t >> 8;                 // 0/1: k-half, mm-half, i-half
  const int m   = t & 63;                 // W2 col
  const int qq  = (t >> 6) & 7;           // W2 32-row slice

  float w1h [32];   // W1[kh*32+k][n]
  float w2s [32];   // W2[qq*32+j][m]      (column slice)
  float w2r2[32];   // W2[n][kh*32+mm]     (row half)
  float zb8[8];     // z1bp finals for rows kh*8..+8
  float g1v[16];    // g1 column (P5 -> P6)
  float xa0, xa1;   // XA prefetch (rows t>>6 and +8, col t&63)

  const float* W1h = W1g + h * HFsz * HF4sz;
  const float* W2h = W2g + h * HF4sz * HFsz;
#pragma unroll
  for (int k = 0; k < 32; ++k) w1h[k] = W1h[(kh * 32 + k) * 256 + n];
#pragma unroll
  for (int j = 0; j < 32; ++j) w2s[j] = W2h[(qq * 32 + j) * 64 + m];
#pragma unroll
  for (int j = 0; j < 32; ++j) w2r2[j] = W2h[n * 64 + kh * 32 + j];

  {
    const int cb0 = (b * Lsz) * Csz + h * HFsz;
    if (t < 16) sCoBuf[t] = coeff[(bh * NCsz + 0) * CSsz + t];
    xa0 = XA[cb0 + (t >> 6) * 1024 + m];
    xa1 = XA[cb0 + ((t >> 6) + 8) * 1024 + m];
  }
  __syncthreads();

#pragma unroll 1
  for (int nc = 0; nc < NCsz; ++nc) {
    const int cur = nc & 1, nxt = cur ^ 1;
    const int cb  = (b * Lsz + nc * CSsz) * Csz + h * HFsz;
    const int nc1 = (nc + 1) & (NCsz - 1);
    const int cb1 = (b * Lsz + nc1 * CSsz) * Csz + h * HFsz;
    const float* __restrict__ xbG = XBuf  + cb;   // 16 rows, stride 1024
    const float* __restrict__ xcG = XCbuf + cb;
    const float* __restrict__ xb8 = xbG + kh * 32;
    const float* __restrict__ xc8 = xcG + kh * 32;

    const float cl = sCoBuf[cur * 16 + 15];
    float conext = 0.f;
    if (t < 16) conext = coeff[(bh * NCsz + nc1) * CSsz + t];

    // ---- P1: Z1 + z1bp K-half partials ----------------------------------
    {
      float zz[16];
#pragma unroll
      for (int i = 0; i < 16; ++i) zz[i] = 0.f;
#pragma unroll
      for (int k = 0; k < 32; k += 4) {
        const float wa = w1h[k], wb = w1h[k + 1], wc = w1h[k + 2], wd = w1h[k + 3];
#pragma unroll
        for (int i = 0; i < 16; ++i) {
          const float4 x = *(const float4*)&xb8[i * 1024 + k];
          zz[i] = fmaf(x.w, wd, fmaf(x.z, wc, fmaf(x.y, wb, fmaf(x.x, wa, zz[i]))));
        }
      }
      float* dstZ = kh ? sZ1b : sZ1;
#pragma unroll
      for (int i = 0; i < 16; ++i) dstZ[i * 260 + n] = zz[i];
      // z1bp partial
#pragma unroll
      for (int i = 0; i < 16; ++i) zz[i] = 0.f;
#pragma unroll
      for (int k = 0; k < 32; k += 4) {
        const float wa = w1h[k], wb = w1h[k + 1], wc = w1h[k + 2], wd = w1h[k + 3];
#pragma unroll
        for (int i = 0; i < 16; ++i) {
          const float4 x = *(const float4*)&xc8[i * 1024 + k];
          zz[i] = fmaf(x.w, wd, fmaf(x.z, wc, fmaf(x.y, wb, fmaf(x.x, wa, zz[i]))));
        }
      }
      if (!kh) {
#pragma unroll
        for (int i = 0; i < 16; ++i) sPg[i * 256 + n] = zz[i];
      } else {
        // stash in zb8-extended form via registers: keep all 16 to P1.5
        // (use g1v as scratch to avoid a second 16-array: dead until P5)
#pragma unroll
        for (int i = 0; i < 16; ++i) g1v[i] = zz[i];
      }
    }
    __syncthreads();

    // ---- P1.5: Z1 reduce; kh1: z1bp combine; kh0: Attn1 -----------------
    {
      const int r0i = t >> 6;          // 0..7
#pragma unroll
      for (int r = 0; r < 2; ++r) {
        const int idx = (r0i + 8 * r) * 260 + m * 4;
        float4 a = *(const float4*)&sZ1[idx];
        const float4 p = *(const float4*)&sZ1b[idx];
        a.x += p.x; a.y += p.y; a.z += p.z; a.w += p.w;
        *(float4*)&sZ1[idx] = a;
      }
    }
    if (kh) {
#pragma unroll
      for (int j = 0; j < 16; ++j) g1v[j] += sPg[j * 256 + n];
#pragma unroll
      for (int j = 0; j < 8; ++j) sPg[j * 256 + n] = g1v[j];  // kh0 finals
#pragma unroll
      for (int r = 0; r < 8; ++r) zb8[r] = g1v[8 + r];        // own rows 8-15
    } else {
      const int ia = n >> 4, ja = n & 15;
      float a0 = 0.f, a1 = 0.f;
      if (ja <= ia) {
#pragma unroll
        for (int k = 0; k < 64; k += 8) {
          const float4 c0 = *(const float4*)&xcG[ia * 1024 + k];
          const float4 b0 = *(const float4*)&xbG[ja * 1024 + k];
          const float4 c1 = *(const float4*)&xcG[ia * 1024 + k + 4];
          const float4 b1 = *(const float4*)&xbG[ja * 1024 + k + 4];
          a0 = fmaf(c0.w, b0.w, fmaf(c0.z, b0.z, fmaf(c0.y, b0.y, fmaf(c0.x, b0.x, a0))));
          a1 = fmaf(c1.w, b1.w, fmaf(c1.z, b1.z, fmaf(c1.y, b1.y, fmaf(c1.x, b1.x, a1))));
        }
      }
      sA1[ia * 17 + ja] = a0 + a1;
    }
    __syncthreads();

    // ---- P2: Z2 partials (role qq,m) -> sP ------------------------------
    {
      const int ko = qq << 5;
      float acc[16];
#pragma unroll
      for (int i = 0; i < 16; ++i) acc[i] = 0.f;
#pragma unroll
      for (int kk = 0; kk < 32; kk += 4) {
        const float wa = w2s[kk], wb = w2s[kk + 1], wc = w2s[kk + 2], wd = w2s[kk + 3];
#pragma unroll
        for (int i = 0; i < 16; ++i) {
          const float4 z = *(const float4*)&sZ1[i * 260 + ko + kk];
          acc[i] = fmaf(z.w, wd, fmaf(z.z, wc, fmaf(z.y, wb, fmaf(z.x, wa, acc[i]))));
        }
      }
#pragma unroll
      for (int i = 0; i < 16; ++i) sP[(qq << 10) + (i << 6) + m] = acc[i];
    }
    __syncthreads();

    // ---- P3: g2 = reduce(sP) - XA -> sg2 ; coeff ; kh0 z1bp read-back ---
    {
      const int i3 = t >> 6;
      float v0 = 0.f, v1 = 0.f;
#pragma unroll
      for (int p = 0; p < 8; ++p) {
        v0 += sP[(p << 10) + (i3 << 6) + m];
        v1 += sP[(p << 10) + ((i3 + 8) << 6) + m];
      }
      v0 -= xa0; v1 -= xa1;
      sg2[i3 * 68 + m] = v0;
      sg2[(i3 + 8) * 68 + m] = v1;
      xa0 = XA[cb1 + i3 * 1024 + m];
      xa1 = XA[cb1 + (i3 + 8) * 1024 + m];
      if (t < 16) sCoBuf[nxt * 16 + t] = conext;
    }
    if (!kh) {
#pragma unroll
      for (int r = 0; r < 8; ++r) zb8[r] = sPg[r * 256 + n];
    }
    __syncthreads();

    // ---- P4: g1 mm-half partials -> sPg + fused w2r2 update (i-outer) ---
    {
      const int mb = kh << 5;
#pragma unroll
      for (int i = 0; i < 16; ++i) {
        const float s = cl * sZ1[i * 260 + n];
        float acc = 0.f;
#pragma unroll
        for (int mm = 0; mm < 32; mm += 4) {
          const float4 g = *(const float4*)&sg2[i * 68 + mb + mm];
          acc = fmaf(g.w, w2r2[mm + 3], fmaf(g.z, w2r2[mm + 2],
                fmaf(g.y, w2r2[mm + 1], fmaf(g.x, w2r2[mm], acc))));
          w2r2[mm + 0] -= s * g.x; w2r2[mm + 1] -= s * g.y;
          w2r2[mm + 2] -= s * g.z; w2r2[mm + 3] -= s * g.w;
        }
        sPg[(kh << 12) + (i << 8) + n] = acc;
      }
    }
    __syncthreads();

    // ---- P5: Z1b rows [kh*8,+8) finalize -> sZ1b ------------------------
    {
#pragma unroll
      for (int j = 0; j < 16; ++j)
        g1v[j] = sPg[(j << 8) + n] + sPg[4096 + (j << 8) + n];
#pragma unroll
      for (int r = 0; r < 8; ++r) {
        const int i = kh * 8 + r;
        float at = 0.f;
#pragma unroll
        for (int j = 0; j < 16; ++j)
          if (j <= i) at = fmaf(sA1[i * 17 + j], g1v[j], at);
        sZ1b[i * 260 + n] = fmaf(-sCoBuf[cur * 16 + i], at, zb8[r]);
      }
    }
    __syncthreads();

    // ---- P6: W1 half-update | Z2b partials | w2s update | Attn2 half ----
    {
      // (b) W1 half-update first (consumes g1v -> frees 16 regs)
#pragma unroll
      for (int i = 0; i < 16; ++i) {
        const float gi = cl * g1v[i];
#pragma unroll
        for (int k = 0; k < 32; k += 4) {
          const float4 x = *(const float4*)&xb8[i * 1024 + k];
          w1h[k + 0] -= gi * x.x; w1h[k + 1] -= gi * x.y;
          w1h[k + 2] -= gi * x.z; w1h[k + 3] -= gi * x.w;
        }
      }
      // (c) Z2b partials (pre-update w2s)
      const int ko = qq << 5;
      {
        float acc[16];
#pragma unroll
        for (int i = 0; i < 16; ++i) acc[i] = 0.f;
#pragma unroll
        for (int kk = 0; kk < 32; kk += 4) {
          const float wa = w2s[kk], wb = w2s[kk + 1], wc = w2s[kk + 2], wd = w2s[kk + 3];
#pragma unroll
          for (int i = 0; i < 16; ++i) {
            const float4 z = *(const float4*)&sZ1b[i * 260 + ko + kk];
            acc[i] = fmaf(z.w, wd, fmaf(z.z, wc, fmaf(z.y, wb, fmaf(z.x, wa, acc[i]))));
          }
        }
#pragma unroll
        for (int i = 0; i < 16; ++i) sP[(qq << 10) + (i << 6) + m] = acc[i];
      }
      // (d) w2s slice update (i-outer, scalar s2)
#pragma unroll
      for (int i = 0; i < 16; ++i) {
        const float s2 = cl * sg2[i * 68 + m];
#pragma unroll
        for (int kk = 0; kk < 32; kk += 4) {
          const float4 z = *(const float4*)&sZ1[i * 260 + ko + kk];
          w2s[kk + 0] -= s2 * z.x; w2s[kk + 1] -= s2 * z.y;
          w2s[kk + 2] -= s2 * z.z; w2s[kk + 3] -= s2 * z.w;
        }
      }
      // (a) Attn2 K-half
      const int ia = n >> 4, ja = n & 15;
      const int kb = kh << 7;
      float a0 = 0.f, a1 = 0.f;
      if (ja <= ia) {
#pragma unroll
        for (int kk = 0; kk < 128; kk += 8) {
          const float4 p0 = *(const float4*)&sZ1b[ia * 260 + kb + kk];
          const float4 z0 = *(const float4*)&sZ1 [ja * 260 + kb + kk];
          const float4 p1 = *(const float4*)&sZ1b[ia * 260 + kb + kk + 4];
          const float4 z1 = *(const float4*)&sZ1 [ja * 260 + kb + kk + 4];
          a0 = fmaf(p0.w, z0.w, fmaf(p0.z, z0.z, fmaf(p0.y, z0.y, fmaf(p0.x, z0.x, a0))));
          a1 = fmaf(p1.w, z1.w, fmaf(p1.z, z1.z, fmaf(p1.y, z1.y, fmaf(p1.x, z1.x, a1))));
        }
      }
      sA2p[kh * 272 + ia * 17 + ja] = a0 + a1;
    }
    __syncthreads();

    // ---- P7: Z2b reduce + Attn2 combine + store (2 rows/thread).
    //      No trailing barrier: P7 reads sP/sA2p/sg2/sCoBuf[cur]; next P1
    //      writes sZ1/sZ1b/sPg only, and later phases are barrier-gated. --
    {
      const int i3 = t >> 6;
#pragma unroll
      for (int r = 0; r < 2; ++r) {
        const int i = i3 + 8 * r;
        float v = 0.f;
#pragma unroll
        for (int p = 0; p < 8; ++p) v += sP[(p << 10) + (i << 6) + m];
        float at = 0.f;
#pragma unroll
        for (int j = 0; j < 16; ++j)
          at = fmaf(sA2p[i * 17 + j] + sA2p[272 + i * 17 + j],
                    sg2[j * 68 + m], at);
        Out[cb + i * 1024 + m] = v - sCoBuf[cur * 16 + i] * at;
      }
    }
  }
}

// ---------------------------------------------------------------------------
// Workspace (fp32 floats): bXC [0,16.7M) | bXB [16.7M,33.5M) | bZ2b
// [33.5M,50.3M) | bCo [50.3M,+262k).  193 MiB total.  XA (V proj) lives in
// d_out until the final GEMM overwrites it (stream-ordered, safe).
// ---------------------------------------------------------------------------
extern "C" void kernel_launch(void* const* d_in, const int* in_sizes, int n_in,
                              void* d_out, int out_size, void* d_ws, size_t ws_size,
                              hipStream_t stream)
{
  const float* H    = (const float*)d_in[0];
  const float* Wq   = (const float*)d_in[1];
  const float* Wk   = (const float*)d_in[2];
  const float* Wv   = (const float*)d_in[3];
  const float* Wo   = (const float*)d_in[4];
  const float* Wil  = (const float*)d_in[5];
  const float* bil  = (const float*)d_in[6];
  const float* W1   = (const float*)d_in[7];
  const float* W2   = (const float*)d_in[8];
  float* out        = (float*)d_out;

  float* ws    = (float*)d_ws;
  float* bXC   = ws;
  float* bXB   = ws + 16777216;
  float* bZ2b  = ws + 33554432;
  float* bCo   = ws + 50331648;
  float* bXA   = out;

  const int M = Bsz * Lsz, N = Csz, K = Csz;
  dim3 gg(N / 64, M / 64);
  dim3 bb(256);

  gemm64<<<gg, bb, 0, stream>>>(H, Wq, bXC, M, N, K);
  gemm64<<<gg, bb, 0, stream>>>(H, Wk, bXB, M, N, K);
  gemm64<<<gg, bb, 0, stream>>>(H, Wv, bXA, M, N, K);
  ilr_coeff<<<M / 4, 256, 0, stream>>>(H, Wil, bil, bCo);
  ttt_scan<<<Bsz * NHsz, 512, 0, stream>>>(bXA, bXB, bXC, bCo, W1, W2, bZ2b);
  gemm64<<<gg, bb, 0, stream>>>(bZ2b, Wo, out, M, N, K);
}

// Round 9
// 9512.827 us; speedup vs baseline: 6.0548x; 6.0548x over previous
//
#include <hip/hip_runtime.h>

#define Bsz  4
#define Lsz  4096
#define Csz  1024
#define NHsz 16
#define CSsz 16
#define HFsz 64
#define HF4sz 256
#define NCsz 256

typedef __attribute__((ext_vector_type(8))) short  bhalf8;
typedef __attribute__((ext_vector_type(4))) float  floatx4;

// ---------------------------------------------------------------------------
// fp32 -> (bf16 hi, bf16 lo) split, both RNE.  x ~= hi + lo, |err| <~ 2^-18|x|
// ---------------------------------------------------------------------------
__device__ __forceinline__ unsigned short bf_rne(float x) {
  const unsigned u = __float_as_uint(x);
  return (unsigned short)((u + 0x7fffu + ((u >> 16) & 1u)) >> 16);
}
__device__ __forceinline__ void split_rne(float x, unsigned short& h, unsigned short& l) {
  h = bf_rne(x);
  const float hf = __uint_as_float((unsigned)h << 16);
  l = bf_rne(x - hf);
}

// ---------------------------------------------------------------------------
// bulk fp32 -> split-bf16 (hi[], lo[]).  exact-grid: nElem = grid*256*4.
// ---------------------------------------------------------------------------
__global__ __launch_bounds__(256)
void split32(const float* __restrict__ in, unsigned short* __restrict__ hi,
             unsigned short* __restrict__ lo)
{
  const int i = (blockIdx.x * 256 + threadIdx.x) * 4;
  const float4 v = *(const float4*)&in[i];
  ushort4 h, l;
  split_rne(v.x, h.x, l.x);
  split_rne(v.y, h.y, l.y);
  split_rne(v.z, h.z, l.z);
  split_rne(v.w, h.w, l.w);
  *(ushort4*)&hi[i] = h;
  *(ushort4*)&lo[i] = l;
}

// ---------------------------------------------------------------------------
// MFMA GEMM: C[M,N] = A[M,K] @ B[K,N], A pre-split bf16 (hi,lo), B fp32
// converted inline.  Split-bf16 product: hh + hl + lh (ll dropped, ~2^-18).
// 128x128 tile, BK=32, 256 thr = 4 waves (2x2 of 64x64), 16x16x32 bf16 MFMA.
// LDS 40KB -> 4 blocks/CU.  Fragment layout (std CDNA): A row=lane&15,
// k=(lane>>4)*8+e ; B col=lane&15 same k ; D col=lane&15 row=(lane>>4)*4+reg.
// ---------------------------------------------------------------------------
__global__ __launch_bounds__(256)
void gemm_mfma(const unsigned short* __restrict__ Ahi,
               const unsigned short* __restrict__ Alo,
               const float* __restrict__ Bm,
               float* __restrict__ Cm, int M, int N, int K)
{
  __shared__ unsigned short sAh[128 * 40];  // [row][k] stride 40 (pad)
  __shared__ unsigned short sAl[128 * 40];
  __shared__ unsigned short sBh[128 * 40];  // [col][k] (transposed) stride 40
  __shared__ unsigned short sBl[128 * 40];

  const int t    = threadIdx.x;
  const int lane = t & 63, w = t >> 6;
  const int wr   = (w >> 1) * 64, wc = (w & 1) * 64;
  const int row0 = blockIdx.y * 128, col0 = blockIdx.x * 128;
  const int fr   = lane & 15, fk = (lane >> 4) * 8;

  floatx4 acc[4][4];
#pragma unroll
  for (int mi = 0; mi < 4; ++mi)
#pragma unroll
    for (int ni = 0; ni < 4; ++ni) acc[mi][ni] = (floatx4){0.f, 0.f, 0.f, 0.f};

  const int arow = t >> 1, akg = (t & 1) * 16;
  const int bc4  = (t & 31) * 4, bk4 = (t >> 5) * 4;

  for (int k0 = 0; k0 < K; k0 += 32) {
    // ---- stage A (pre-split, straight copy) ----------------------------
    {
      const size_t ga = (size_t)(row0 + arow) * K + k0 + akg;
      const bhalf8 h0 = *(const bhalf8*)&Ahi[ga];
      const bhalf8 h1 = *(const bhalf8*)&Ahi[ga + 8];
      const bhalf8 l0 = *(const bhalf8*)&Alo[ga];
      const bhalf8 l1 = *(const bhalf8*)&Alo[ga + 8];
      *(bhalf8*)&sAh[arow * 40 + akg]     = h0;
      *(bhalf8*)&sAh[arow * 40 + akg + 8] = h1;
      *(bhalf8*)&sAl[arow * 40 + akg]     = l0;
      *(bhalf8*)&sAl[arow * 40 + akg + 8] = l1;
    }
    // ---- stage B (fp32 -> split bf16, transpose to [col][k]) -----------
    {
      const float4 r0 = *(const float4*)&Bm[(size_t)(k0 + bk4 + 0) * N + col0 + bc4];
      const float4 r1 = *(const float4*)&Bm[(size_t)(k0 + bk4 + 1) * N + col0 + bc4];
      const float4 r2 = *(const float4*)&Bm[(size_t)(k0 + bk4 + 2) * N + col0 + bc4];
      const float4 r3 = *(const float4*)&Bm[(size_t)(k0 + bk4 + 3) * N + col0 + bc4];
#define STORE_BCOL(v0, v1, v2, v3, c) do {                                   \
      unsigned short h0_, h1_, h2_, h3_, l0_, l1_, l2_, l3_;                 \
      split_rne(v0, h0_, l0_); split_rne(v1, h1_, l1_);                      \
      split_rne(v2, h2_, l2_); split_rne(v3, h3_, l3_);                      \
      const int off_ = (bc4 + (c)) * 40 + bk4;                               \
      *(unsigned*)&sBh[off_]     = (unsigned)h0_ | ((unsigned)h1_ << 16);    \
      *(unsigned*)&sBh[off_ + 2] = (unsigned)h2_ | ((unsigned)h3_ << 16);    \
      *(unsigned*)&sBl[off_]     = (unsigned)l0_ | ((unsigned)l1_ << 16);    \
      *(unsigned*)&sBl[off_ + 2] = (unsigned)l2_ | ((unsigned)l3_ << 16);    \
    } while (0)
      STORE_BCOL(r0.x, r1.x, r2.x, r3.x, 0);
      STORE_BCOL(r0.y, r1.y, r2.y, r3.y, 1);
      STORE_BCOL(r0.z, r1.z, r2.z, r3.z, 2);
      STORE_BCOL(r0.w, r1.w, r2.w, r3.w, 3);
#undef STORE_BCOL
    }
    __syncthreads();

    // ---- fragments + MFMA ----------------------------------------------
    bhalf8 ah[4], al[4];
#pragma unroll
    for (int mi = 0; mi < 4; ++mi) {
      ah[mi] = *(const bhalf8*)&sAh[(wr + mi * 16 + fr) * 40 + fk];
      al[mi] = *(const bhalf8*)&sAl[(wr + mi * 16 + fr) * 40 + fk];
    }
#pragma unroll
    for (int ni = 0; ni < 4; ++ni) {
      const bhalf8 bh = *(const bhalf8*)&sBh[(wc + ni * 16 + fr) * 40 + fk];
      const bhalf8 bl = *(const bhalf8*)&sBl[(wc + ni * 16 + fr) * 40 + fk];
#pragma unroll
      for (int mi = 0; mi < 4; ++mi) {
        acc[mi][ni] = __builtin_amdgcn_mfma_f32_16x16x32_bf16(ah[mi], bh, acc[mi][ni], 0, 0, 0);
        acc[mi][ni] = __builtin_amdgcn_mfma_f32_16x16x32_bf16(ah[mi], bl, acc[mi][ni], 0, 0, 0);
        acc[mi][ni] = __builtin_amdgcn_mfma_f32_16x16x32_bf16(al[mi], bh, acc[mi][ni], 0, 0, 0);
      }
    }
    __syncthreads();
  }

  // ---- epilogue: D col=lane&15, row=(lane>>4)*4+reg --------------------
  const int er = (lane >> 4) * 4;
#pragma unroll
  for (int mi = 0; mi < 4; ++mi)
#pragma unroll
    for (int ni = 0; ni < 4; ++ni) {
      const size_t base = (size_t)(row0 + wr + mi * 16 + er) * N + col0 + wc + ni * 16 + fr;
#pragma unroll
      for (int j = 0; j < 4; ++j)
        Cm[base + (size_t)j * N] = acc[mi][ni][j];
    }
}

// ---------------------------------------------------------------------------
// ilr -> coeff table (unchanged)
// ---------------------------------------------------------------------------
__global__ __launch_bounds__(256)
void ilr_coeff(const float* __restrict__ H, const float* __restrict__ Wil,
               const float* __restrict__ bil, float* __restrict__ coeff)
{
  __shared__ float sRow[4][1024];
  __shared__ float sP[4][16][17];
  const int t = threadIdx.x;
  const size_t r0 = (size_t)blockIdx.x * 4;
  for (int rr = 0; rr < 4; ++rr)
    for (int c = t; c < 1024; c += 256)
      sRow[rr][c] = H[(r0 + rr) * 1024 + c];
  __syncthreads();
  const int hh = t & 15, sl = t >> 4;
  for (int rr = 0; rr < 4; ++rr) {
    float acc = 0.f;
    for (int kk = 0; kk < 64; ++kk)
      acc += sRow[rr][sl * 64 + kk] * Wil[(sl * 64 + kk) * 16 + hh];
    sP[rr][sl][hh] = acc;
  }
  __syncthreads();
  if (t < 64) {
    const int rr = t >> 4, h2 = t & 15;
    float s = 0.f;
    for (int sl2 = 0; sl2 < 16; ++sl2) s += sP[rr][sl2][h2];
    s += bil[h2];
    const float sig = 1.f / (1.f + expf(-s));
    const int r  = (int)(r0 + rr);
    const int b  = r >> 12, l = r & 4095, nc = l >> 4, cs = l & 15;
    coeff[((b * 16 + h2) * NCsz + nc) * CSsz + cs] = sig / ((float)(cs + 1) * 64.0f);
  }
}

// ---------------------------------------------------------------------------
// TTT scan v5 (EXACT revert to round-4's validated best: 9.0ms, spill-free).
// 512 thr, A/B wave-specialized, wreg overlay, LDS padded to 82432B.
// ---------------------------------------------------------------------------
__global__ __launch_bounds__(512) __attribute__((amdgpu_waves_per_eu(1, 2)))
void ttt_scan(const float* __restrict__ XA, const float* __restrict__ XBuf,
              const float* __restrict__ XCbuf, const float* __restrict__ coeff,
              const float* __restrict__ W1g, const float* __restrict__ W2g,
              float* __restrict__ Out)
{
  __shared__ __attribute__((aligned(16))) float sg2[16 * 68];
  __shared__ __attribute__((aligned(16))) float sZ1[16 * 260];
  __shared__ __attribute__((aligned(16))) float sZ1b[16 * 260];
  __shared__ __attribute__((aligned(16))) float sTmp[10624];
  __shared__ float sA1[16 * 17];
  __shared__ float sA2[16 * 17];
  __shared__ float sCoBuf[2 * 16];

  const int t   = threadIdx.x;
  const int bh  = blockIdx.x;
  const int b   = bh >> 4, h = bh & 15;
  const bool isA = (t < 256);
  const int n   = t & 255;
  const int m   = t & 63, q = (t >> 6) & 3;

  float wreg[128];
#define W1R(k)  wreg[(k)]
#define ZBR(i)  wreg[64 + (i)]
#define G1R(i)  wreg[80 + (i)]
#define W2RR(k) wreg[(k)]
#define W2CR(k) wreg[64 + (k)]

  float xa0, xa1;

  const float* W1h = W1g + h * HFsz * HF4sz;
  const float* W2h = W2g + h * HF4sz * HFsz;
  if (isA) {
#pragma unroll
    for (int k = 0; k < 64; ++k) W1R(k) = W1h[k * 256 + n];
  } else {
#pragma unroll
    for (int mm = 0; mm < 64; ++mm) W2RR(mm) = W2h[n * 64 + mm];
#pragma unroll
    for (int kk = 0; kk < 64; ++kk) W2CR(kk) = W2h[(q * 64 + kk) * 64 + m];
  }

  {
    const int cb0 = (b * Lsz) * Csz + h * HFsz;
    if (t < 16) sCoBuf[t] = coeff[(bh * NCsz + 0) * CSsz + t];
    const int ibr = t >> 6, mm = t & 63;
    xa0 = XA[cb0 + ibr * 1024 + mm];
    xa1 = XA[cb0 + (ibr + 8) * 1024 + mm];
  }
  __syncthreads();

#pragma unroll 1
  for (int nc = 0; nc < NCsz; ++nc) {
    const int cur = nc & 1, nxt = cur ^ 1;
    const int cb  = (b * Lsz + nc * CSsz) * Csz + h * HFsz;
    const int nc1 = (nc + 1) & (NCsz - 1);
    const int cb1 = (b * Lsz + nc1 * CSsz) * Csz + h * HFsz;
    const float* __restrict__ xbG = XBuf  + cb;
    const float* __restrict__ xcG = XCbuf + cb;

    const float cl = sCoBuf[cur * 16 + 15];
    float conext = 0.f;
    if (isA && t < 16) conext = coeff[(bh * NCsz + nc1) * CSsz + t];

    // ---- P1 -------------------------------------------------------------
    if (isA) {
      float acc[16];
#pragma unroll
      for (int i = 0; i < 16; ++i) {
        float a0 = 0.f, a1 = 0.f;
#pragma unroll
        for (int k = 0; k < 64; k += 8) {
          const float4 x0 = *(const float4*)&xbG[i * 1024 + k];
          const float4 x1 = *(const float4*)&xbG[i * 1024 + k + 4];
          a0 = fmaf(x0.w, W1R(k + 3), fmaf(x0.z, W1R(k + 2),
               fmaf(x0.y, W1R(k + 1), fmaf(x0.x, W1R(k), a0))));
          a1 = fmaf(x1.w, W1R(k + 7), fmaf(x1.z, W1R(k + 6),
               fmaf(x1.y, W1R(k + 5), fmaf(x1.x, W1R(k + 4), a1))));
        }
        acc[i] = a0 + a1;
      }
#pragma unroll
      for (int i = 0; i < 16; ++i) sZ1[i * 260 + n] = acc[i];
    } else {
      const int ia = n >> 4, ja = n & 15;
      float a0 = 0.f, a1 = 0.f;
      if (ja <= ia) {
#pragma unroll
        for (int k = 0; k < 64; k += 8) {
          const float4 c0 = *(const float4*)&xcG[ia * 1024 + k];
          const float4 b0 = *(const float4*)&xbG[ja * 1024 + k];
          const float4 c1 = *(const float4*)&xcG[ia * 1024 + k + 4];
          const float4 b1 = *(const float4*)&xbG[ja * 1024 + k + 4];
          a0 = fmaf(c0.w, b0.w, fmaf(c0.z, b0.z, fmaf(c0.y, b0.y, fmaf(c0.x, b0.x, a0))));
          a1 = fmaf(c1.w, b1.w, fmaf(c1.z, b1.z, fmaf(c1.y, b1.y, fmaf(c1.x, b1.x, a1))));
        }
      }
      sA1[ia * 17 + ja] = a0 + a1;
    }
    __syncthreads();

    // ---- P2 -------------------------------------------------------------
    if (isA) {
#pragma unroll
      for (int i = 0; i < 16; ++i) {
        float a0 = 0.f, a1 = 0.f;
#pragma unroll
        for (int k = 0; k < 64; k += 8) {
          const float4 x0 = *(const float4*)&xcG[i * 1024 + k];
          const float4 x1 = *(const float4*)&xcG[i * 1024 + k + 4];
          a0 = fmaf(x0.w, W1R(k + 3), fmaf(x0.z, W1R(k + 2),
               fmaf(x0.y, W1R(k + 1), fmaf(x0.x, W1R(k), a0))));
          a1 = fmaf(x1.w, W1R(k + 7), fmaf(x1.z, W1R(k + 6),
               fmaf(x1.y, W1R(k + 5), fmaf(x1.x, W1R(k + 4), a1))));
        }
        ZBR(i) = a0 + a1;
      }
    } else {
      const int qo = q << 6;
      float acc[16];
#pragma unroll
      for (int i = 0; i < 16; ++i) acc[i] = 0.f;
#pragma unroll
      for (int kk = 0; kk < 64; kk += 4) {
        const float wa = W2CR(kk), wb = W2CR(kk + 1), wc = W2CR(kk + 2), wd = W2CR(kk + 3);
#pragma unroll
        for (int i = 0; i < 16; ++i) {
          const float4 z = *(const float4*)&sZ1[i * 260 + qo + kk];
          acc[i] = fmaf(z.w, wd, fmaf(z.z, wc, fmaf(z.y, wb, fmaf(z.x, wa, acc[i]))));
        }
      }
#pragma unroll
      for (int i = 0; i < 16; ++i) sTmp[(q << 10) + (i << 6) + m] = acc[i];
    }
    __syncthreads();

    // ---- P3 -------------------------------------------------------------
    {
      const int ibr = t >> 6, mm = t & 63;
      const int i1 = ibr + 8;
      float v0 = sTmp[ibr * 64 + mm] + sTmp[1024 + ibr * 64 + mm]
               + sTmp[2048 + ibr * 64 + mm] + sTmp[3072 + ibr * 64 + mm] - xa0;
      float v1 = sTmp[i1 * 64 + mm] + sTmp[1024 + i1 * 64 + mm]
               + sTmp[2048 + i1 * 64 + mm] + sTmp[3072 + i1 * 64 + mm] - xa1;
      sg2[ibr * 68 + mm] = v0;
      sg2[i1 * 68 + mm]  = v1;
      xa0 = XA[cb1 + ibr * 1024 + mm];
      xa1 = XA[cb1 + i1 * 1024 + mm];
      if (t < 16) sCoBuf[nxt * 16 + t] = conext;
    }
    __syncthreads();

    // ---- P4 -------------------------------------------------------------
    if (!isA) {
      float s[16];
#pragma unroll
      for (int i = 0; i < 16; ++i) s[i] = cl * sZ1[i * 260 + n];
      float acc[16];
#pragma unroll
      for (int i = 0; i < 16; ++i) acc[i] = 0.f;
#pragma unroll
      for (int mm = 0; mm < 64; mm += 4) {
        const float wa = W2RR(mm), wb = W2RR(mm + 1), wc = W2RR(mm + 2), wd = W2RR(mm + 3);
        float d0 = 0.f, d1 = 0.f, d2 = 0.f, d3 = 0.f;
#pragma unroll
        for (int i = 0; i < 16; ++i) {
          const float4 g = *(const float4*)&sg2[i * 68 + mm];
          acc[i] = fmaf(g.w, wd, fmaf(g.z, wc, fmaf(g.y, wb, fmaf(g.x, wa, acc[i]))));
          d0 = fmaf(s[i], g.x, d0); d1 = fmaf(s[i], g.y, d1);
          d2 = fmaf(s[i], g.z, d2); d3 = fmaf(s[i], g.w, d3);
        }
        W2RR(mm + 0) -= d0; W2RR(mm + 1) -= d1; W2RR(mm + 2) -= d2; W2RR(mm + 3) -= d3;
      }
#pragma unroll
      for (int i = 0; i < 16; ++i) sTmp[i * 256 + n] = acc[i];
    }
    __syncthreads();

    // ---- P5 -------------------------------------------------------------
    if (isA) {
#pragma unroll
      for (int j = 0; j < 16; ++j) G1R(j) = sTmp[j * 256 + n];
#pragma unroll
      for (int i = 0; i < 16; ++i) {
        float at = 0.f;
#pragma unroll
        for (int j = 0; j <= i; ++j) at = fmaf(sA1[i * 17 + j], G1R(j), at);
        ZBR(i) = fmaf(-sCoBuf[cur * 16 + i], at, ZBR(i));
        sZ1b[i * 260 + n] = ZBR(i);
      }
    }
    __syncthreads();

    // ---- P6 -------------------------------------------------------------
    if (isA) {
      const int ia = n >> 4, ja = n & 15;
      float a0 = 0.f, a1 = 0.f, a2 = 0.f, a3 = 0.f;
      if (ja <= ia) {
#pragma unroll
        for (int kk = 0; kk < 256; kk += 16) {
          const float4 p0 = *(const float4*)&sZ1b[ia * 260 + kk];
          const float4 z0 = *(const float4*)&sZ1 [ja * 260 + kk];
          const float4 p1 = *(const float4*)&sZ1b[ia * 260 + kk + 4];
          const float4 z1 = *(const float4*)&sZ1 [ja * 260 + kk + 4];
          const float4 p2 = *(const float4*)&sZ1b[ia * 260 + kk + 8];
          const float4 z2 = *(const float4*)&sZ1 [ja * 260 + kk + 8];
          const float4 p3 = *(const float4*)&sZ1b[ia * 260 + kk + 12];
          const float4 z3 = *(const float4*)&sZ1 [ja * 260 + kk + 12];
          a0 = fmaf(p0.w, z0.w, fmaf(p0.z, z0.z, fmaf(p0.y, z0.y, fmaf(p0.x, z0.x, a0))));
          a1 = fmaf(p1.w, z1.w, fmaf(p1.z, z1.z, fmaf(p1.y, z1.y, fmaf(p1.x, z1.x, a1))));
          a2 = fmaf(p2.w, z2.w, fmaf(p2.z, z2.z, fmaf(p2.y, z2.y, fmaf(p2.x, z2.x, a2))));
          a3 = fmaf(p3.w, z3.w, fmaf(p3.z, z3.z, fmaf(p3.y, z3.y, fmaf(p3.x, z3.x, a3))));
        }
      }
      sA2[ia * 17 + ja] = (a0 + a1) + (a2 + a3);
#pragma unroll
      for (int i = 0; i < 16; ++i) {
        const float gi = cl * G1R(i);
#pragma unroll
        for (int k = 0; k < 64; k += 4) {
          const float4 x = *(const float4*)&xbG[i * 1024 + k];
          W1R(k + 0) -= gi * x.x; W1R(k + 1) -= gi * x.y;
          W1R(k + 2) -= gi * x.z; W1R(k + 3) -= gi * x.w;
        }
      }
    } else {
      const int qo = q << 6;
      float acc[16];
#pragma unroll
      for (int i = 0; i < 16; ++i) acc[i] = 0.f;
#pragma unroll
      for (int kk = 0; kk < 64; kk += 4) {
        const float wa = W2CR(kk), wb = W2CR(kk + 1), wc = W2CR(kk + 2), wd = W2CR(kk + 3);
#pragma unroll
        for (int i = 0; i < 16; ++i) {
          const float4 z = *(const float4*)&sZ1b[i * 260 + qo + kk];
          acc[i] = fmaf(z.w, wd, fmaf(z.z, wc, fmaf(z.y, wb, fmaf(z.x, wa, acc[i]))));
        }
      }
#pragma unroll
      for (int i = 0; i < 16; ++i) sTmp[(q << 10) + (i << 6) + m] = acc[i];
      float s2[16];
#pragma unroll
      for (int i = 0; i < 16; ++i) s2[i] = cl * sg2[i * 68 + m];
#pragma unroll
      for (int kk = 0; kk < 64; kk += 4) {
        float d0 = 0.f, d1 = 0.f, d2 = 0.f, d3 = 0.f;
#pragma unroll
        for (int i = 0; i < 16; ++i) {
          const float4 z = *(const float4*)&sZ1[i * 260 + qo + kk];
          d0 = fmaf(s2[i], z.x, d0); d1 = fmaf(s2[i], z.y, d1);
          d2 = fmaf(s2[i], z.z, d2); d3 = fmaf(s2[i], z.w, d3);
        }
        W2CR(kk + 0) -= d0; W2CR(kk + 1) -= d1; W2CR(kk + 2) -= d2; W2CR(kk + 3) -= d3;
      }
    }
    __syncthreads();

    // ---- P7 -------------------------------------------------------------
    if (isA) {
      const int q4 = n >> 6, mm = n & 63;
#pragma unroll
      for (int r = 0; r < 4; ++r) {
        const int i = q4 + 4 * r;
        float v = sTmp[i * 64 + mm] + sTmp[1024 + i * 64 + mm]
                + sTmp[2048 + i * 64 + mm] + sTmp[3072 + i * 64 + mm];
        float at = 0.f;
#pragma unroll
        for (int j = 0; j < 16; ++j) at = fmaf(sA2[i * 17 + j], sg2[j * 68 + mm], at);
        Out[cb + i * 1024 + mm] = v - sCoBuf[cur * 16 + i] * at;
      }
    }
  }
#undef W1R
#undef ZBR
#undef G1R
#undef W2RR
#undef W2CR
}

// ---------------------------------------------------------------------------
// Workspace (fp32 floats): bXC [0,16.7M) | bXB [16.7M,33.5M) | bZ2b
// [33.5M,50.3M) | bCo [50.3M,+262k).  193 MiB total (unchanged).
// H-split (32MB hi + 32MB lo ushort) lives in the bZ2b region (dead until
// the scan writes Z2b).  Z2b-split lives in the bXC region (dead after the
// scan's last read).  XA lives in d_out until the final GEMM overwrites it.
// ---------------------------------------------------------------------------
extern "C" void kernel_launch(void* const* d_in, const int* in_sizes, int n_in,
                              void* d_out, int out_size, void* d_ws, size_t ws_size,
                              hipStream_t stream)
{
  const float* H    = (const float*)d_in[0];
  const float* Wq   = (const float*)d_in[1];
  const float* Wk   = (const float*)d_in[2];
  const float* Wv   = (const float*)d_in[3];
  const float* Wo   = (const float*)d_in[4];
  const float* Wil  = (const float*)d_in[5];
  const float* bil  = (const float*)d_in[6];
  const float* W1   = (const float*)d_in[7];
  const float* W2   = (const float*)d_in[8];
  float* out        = (float*)d_out;

  float* ws    = (float*)d_ws;
  float* bXC   = ws;
  float* bXB   = ws + 16777216;
  float* bZ2b  = ws + 33554432;
  float* bCo   = ws + 50331648;
  float* bXA   = out;

  unsigned short* hHi = (unsigned short*)bZ2b;       // 16M ushort = 32MB
  unsigned short* hLo = hHi + 16777216;              // +32MB (fills bZ2b)
  unsigned short* zHi = (unsigned short*)bXC;        // reused after scan
  unsigned short* zLo = zHi + 16777216;

  const int M = Bsz * Lsz, N = Csz, K = Csz;
  dim3 gm(N / 128, M / 128);   // 8 x 128
  dim3 bm(256);

  split32<<<16384, 256, 0, stream>>>(H, hHi, hLo);
  gemm_mfma<<<gm, bm, 0, stream>>>(hHi, hLo, Wq, bXC, M, N, K);
  gemm_mfma<<<gm, bm, 0, stream>>>(hHi, hLo, Wk, bXB, M, N, K);
  gemm_mfma<<<gm, bm, 0, stream>>>(hHi, hLo, Wv, bXA, M, N, K);
  ilr_coeff<<<M / 4, 256, 0, stream>>>(H, Wil, bil, bCo);
  ttt_scan<<<Bsz * NHsz, 512, 0, stream>>>(bXA, bXB, bXC, bCo, W1, W2, bZ2b);
  split32<<<16384, 256, 0, stream>>>(bZ2b, zHi, zLo);
  gemm_mfma<<<gm, bm, 0, stream>>>(zHi, zLo, Wo, out, M, N, K);
}

// Round 10
// 8694.126 us; speedup vs baseline: 6.6250x; 1.0942x over previous
//
#include <hip/hip_runtime.h>

#define Bsz  4
#define Lsz  4096
#define Csz  1024
#define NHsz 16
#define CSsz 16
#define HFsz 64
#define HF4sz 256
#define NCsz 256

typedef __attribute__((ext_vector_type(8))) short  bhalf8;
typedef __attribute__((ext_vector_type(4))) float  floatx4;

// ---------------------------------------------------------------------------
// fp32 -> bf16 helpers.  tsplit: trunc-hi + RNE-lo (x ~= h+l, |err|~2^-16|x|).
// ---------------------------------------------------------------------------
__device__ __forceinline__ unsigned short bf_rne(float x) {
  const unsigned u = __float_as_uint(x);
  return (unsigned short)((u + 0x7fffu + ((u >> 16) & 1u)) >> 16);
}
__device__ __forceinline__ void split_rne(float x, unsigned short& h, unsigned short& l) {
  h = bf_rne(x);
  const float hf = __uint_as_float((unsigned)h << 16);
  l = bf_rne(x - hf);
}
__device__ __forceinline__ void tsplit(float x, unsigned short& h, unsigned short& l) {
  const unsigned u = __float_as_uint(x);
  h = (unsigned short)(u >> 16);
  const float r = x - __uint_as_float(u & 0xffff0000u);
  l = bf_rne(r);
}
__device__ __forceinline__ void split_frag8(const float* __restrict__ x,
                                            bhalf8& h, bhalf8& l) {
#pragma unroll
  for (int e = 0; e < 8; ++e) {
    unsigned short hs, ls;
    tsplit(x[e], hs, ls);
    h[e] = (short)hs; l[e] = (short)ls;
  }
}
__device__ __forceinline__ float recon2(unsigned short h, unsigned short l) {
  return __uint_as_float((unsigned)h << 16) + __uint_as_float((unsigned)l << 16);
}

#define MFMA3(acc, ah, al, bh, bl)                                            \
  acc = __builtin_amdgcn_mfma_f32_16x16x32_bf16(ah, bh, acc, 0, 0, 0);        \
  acc = __builtin_amdgcn_mfma_f32_16x16x32_bf16(ah, bl, acc, 0, 0, 0);        \
  acc = __builtin_amdgcn_mfma_f32_16x16x32_bf16(al, bh, acc, 0, 0, 0);

// ---------------------------------------------------------------------------
// bulk fp32 -> split-bf16 (hi[], lo[]) for the big GEMMs (RNE split).
// ---------------------------------------------------------------------------
__global__ __launch_bounds__(256)
void split32(const float* __restrict__ in, unsigned short* __restrict__ hi,
             unsigned short* __restrict__ lo)
{
  const int i = (blockIdx.x * 256 + threadIdx.x) * 4;
  const float4 v = *(const float4*)&in[i];
  ushort4 h, l;
  split_rne(v.x, h.x, l.x);
  split_rne(v.y, h.y, l.y);
  split_rne(v.z, h.z, l.z);
  split_rne(v.w, h.w, l.w);
  *(ushort4*)&hi[i] = h;
  *(ushort4*)&lo[i] = l;
}

// ---------------------------------------------------------------------------
// MFMA GEMM (validated round 9): C = A@B, A pre-split, B fp32 inline-split.
// ---------------------------------------------------------------------------
__global__ __launch_bounds__(256)
void gemm_mfma(const unsigned short* __restrict__ Ahi,
               const unsigned short* __restrict__ Alo,
               const float* __restrict__ Bm,
               float* __restrict__ Cm, int M, int N, int K)
{
  __shared__ unsigned short sAh[128 * 40];
  __shared__ unsigned short sAl[128 * 40];
  __shared__ unsigned short sBh[128 * 40];
  __shared__ unsigned short sBl[128 * 40];

  const int t    = threadIdx.x;
  const int lane = t & 63, w = t >> 6;
  const int wr   = (w >> 1) * 64, wc = (w & 1) * 64;
  const int row0 = blockIdx.y * 128, col0 = blockIdx.x * 128;
  const int fr   = lane & 15, fk = (lane >> 4) * 8;

  floatx4 acc[4][4];
#pragma unroll
  for (int mi = 0; mi < 4; ++mi)
#pragma unroll
    for (int ni = 0; ni < 4; ++ni) acc[mi][ni] = (floatx4){0.f, 0.f, 0.f, 0.f};

  const int arow = t >> 1, akg = (t & 1) * 16;
  const int bc4  = (t & 31) * 4, bk4 = (t >> 5) * 4;

  for (int k0 = 0; k0 < K; k0 += 32) {
    {
      const size_t ga = (size_t)(row0 + arow) * K + k0 + akg;
      const bhalf8 h0 = *(const bhalf8*)&Ahi[ga];
      const bhalf8 h1 = *(const bhalf8*)&Ahi[ga + 8];
      const bhalf8 l0 = *(const bhalf8*)&Alo[ga];
      const bhalf8 l1 = *(const bhalf8*)&Alo[ga + 8];
      *(bhalf8*)&sAh[arow * 40 + akg]     = h0;
      *(bhalf8*)&sAh[arow * 40 + akg + 8] = h1;
      *(bhalf8*)&sAl[arow * 40 + akg]     = l0;
      *(bhalf8*)&sAl[arow * 40 + akg + 8] = l1;
    }
    {
      const float4 r0 = *(const float4*)&Bm[(size_t)(k0 + bk4 + 0) * N + col0 + bc4];
      const float4 r1 = *(const float4*)&Bm[(size_t)(k0 + bk4 + 1) * N + col0 + bc4];
      const float4 r2 = *(const float4*)&Bm[(size_t)(k0 + bk4 + 2) * N + col0 + bc4];
      const float4 r3 = *(const float4*)&Bm[(size_t)(k0 + bk4 + 3) * N + col0 + bc4];
#define STORE_BCOL(v0, v1, v2, v3, c) do {                                   \
      unsigned short h0_, h1_, h2_, h3_, l0_, l1_, l2_, l3_;                 \
      split_rne(v0, h0_, l0_); split_rne(v1, h1_, l1_);                      \
      split_rne(v2, h2_, l2_); split_rne(v3, h3_, l3_);                      \
      const int off_ = (bc4 + (c)) * 40 + bk4;                               \
      *(unsigned*)&sBh[off_]     = (unsigned)h0_ | ((unsigned)h1_ << 16);    \
      *(unsigned*)&sBh[off_ + 2] = (unsigned)h2_ | ((unsigned)h3_ << 16);    \
      *(unsigned*)&sBl[off_]     = (unsigned)l0_ | ((unsigned)l1_ << 16);    \
      *(unsigned*)&sBl[off_ + 2] = (unsigned)l2_ | ((unsigned)l3_ << 16);    \
    } while (0)
      STORE_BCOL(r0.x, r1.x, r2.x, r3.x, 0);
      STORE_BCOL(r0.y, r1.y, r2.y, r3.y, 1);
      STORE_BCOL(r0.z, r1.z, r2.z, r3.z, 2);
      STORE_BCOL(r0.w, r1.w, r2.w, r3.w, 3);
#undef STORE_BCOL
    }
    __syncthreads();

    bhalf8 ah[4], al[4];
#pragma unroll
    for (int mi = 0; mi < 4; ++mi) {
      ah[mi] = *(const bhalf8*)&sAh[(wr + mi * 16 + fr) * 40 + fk];
      al[mi] = *(const bhalf8*)&sAl[(wr + mi * 16 + fr) * 40 + fk];
    }
#pragma unroll
    for (int ni = 0; ni < 4; ++ni) {
      const bhalf8 bh = *(const bhalf8*)&sBh[(wc + ni * 16 + fr) * 40 + fk];
      const bhalf8 bl = *(const bhalf8*)&sBl[(wc + ni * 16 + fr) * 40 + fk];
#pragma unroll
      for (int mi = 0; mi < 4; ++mi) {
        acc[mi][ni] = __builtin_amdgcn_mfma_f32_16x16x32_bf16(ah[mi], bh, acc[mi][ni], 0, 0, 0);
        acc[mi][ni] = __builtin_amdgcn_mfma_f32_16x16x32_bf16(ah[mi], bl, acc[mi][ni], 0, 0, 0);
        acc[mi][ni] = __builtin_amdgcn_mfma_f32_16x16x32_bf16(al[mi], bh, acc[mi][ni], 0, 0, 0);
      }
    }
    __syncthreads();
  }

  const int er = (lane >> 4) * 4;
#pragma unroll
  for (int mi = 0; mi < 4; ++mi)
#pragma unroll
    for (int ni = 0; ni < 4; ++ni) {
      const size_t base = (size_t)(row0 + wr + mi * 16 + er) * N + col0 + wc + ni * 16 + fr;
#pragma unroll
      for (int j = 0; j < 4; ++j)
        Cm[base + (size_t)j * N] = acc[mi][ni][j];
    }
}

// ---------------------------------------------------------------------------
// ilr -> coeff table (unchanged)
// ---------------------------------------------------------------------------
__global__ __launch_bounds__(256)
void ilr_coeff(const float* __restrict__ H, const float* __restrict__ Wil,
               const float* __restrict__ bil, float* __restrict__ coeff)
{
  __shared__ float sRow[4][1024];
  __shared__ float sP[4][16][17];
  const int t = threadIdx.x;
  const size_t r0 = (size_t)blockIdx.x * 4;
  for (int rr = 0; rr < 4; ++rr)
    for (int c = t; c < 1024; c += 256)
      sRow[rr][c] = H[(r0 + rr) * 1024 + c];
  __syncthreads();
  const int hh = t & 15, sl = t >> 4;
  for (int rr = 0; rr < 4; ++rr) {
    float acc = 0.f;
    for (int kk = 0; kk < 64; ++kk)
      acc += sRow[rr][sl * 64 + kk] * Wil[(sl * 64 + kk) * 16 + hh];
    sP[rr][sl][hh] = acc;
  }
  __syncthreads();
  if (t < 64) {
    const int rr = t >> 4, h2 = t & 15;
    float s = 0.f;
    for (int sl2 = 0; sl2 < 16; ++sl2) s += sP[rr][sl2][h2];
    s += bil[h2];
    const float sig = 1.f / (1.f + expf(-s));
    const int r  = (int)(r0 + rr);
    const int b  = r >> 12, l = r & 4095, nc = l >> 4, cs = l & 15;
    coeff[((b * 16 + h2) * NCsz + nc) * CSsz + cs] = sig / ((float)(cs + 1) * 64.0f);
  }
}

// ---------------------------------------------------------------------------
// TTT scan v12 — MFMA.  512 thr: A = waves 0-3 (W1 side), B = waves 4-7 (W2).
//
// Weight masters fp32 in REGISTERS in MFMA-fragment layout:
//   A lane (w,fr,fg): w1m[tt*16+ks*8+e] = W1[32ks+8fg+e][64w+16tt+fr]
//   B lane (wb,fr,fg): w2m[ks*8+e]      = W2[32ks+8fg+e][16wb+fr]
// Forward matmuls (Z1,z1bp,Z2,g1,Z2b,Attn2) run on the matrix pipe with
// trunc-hi+RNE-lo split (~2^-16 rel err, validated by gemm_mfma).  Weight
// updates stay exact fp32 VALU on the masters (single distribution now).
// g1 needs W2 in [k][m] major -> split-bf16 LDS copy rebuilt by B in P7.
// Phases: P1'(A: Z1+z1bp MFMA | B: Attn1) P2'(B: Z2,g2 | A: XBt stage)
// P4(B: g1 MFMA) P5(A: Z1b) P6(A: Attn2-part+W1up | B: Z2b+W2up)
// P7(B: apply+store+rebuild+XA prefetch, no trailing barrier).  6 barriers.
// LDS = 163,776 B (limit 163,840).
// ---------------------------------------------------------------------------
__global__ __launch_bounds__(512)
void ttt_scan(const float* __restrict__ XA, const float* __restrict__ XBuf,
              const float* __restrict__ XCbuf, const float* __restrict__ coeff,
              const float* __restrict__ W1g, const float* __restrict__ W2g,
              float* __restrict__ Out)
{
  __shared__ __attribute__((aligned(16))) unsigned short sW2h[256 * 72]; // 36864
  __shared__ __attribute__((aligned(16))) unsigned short sW2l[256 * 72]; // 36864
  __shared__ __attribute__((aligned(16))) unsigned short sZ1h[16 * 264]; // 8448
  __shared__ __attribute__((aligned(16))) unsigned short sZ1l[16 * 264];
  __shared__ __attribute__((aligned(16))) unsigned short sZbh[16 * 264];
  __shared__ __attribute__((aligned(16))) unsigned short sZbl[16 * 264];
  __shared__ __attribute__((aligned(16))) float sZ1t[256 * 20];          // 20480
  __shared__ __attribute__((aligned(16))) float sG1 [256 * 20];          // 20480
  __shared__ __attribute__((aligned(16))) unsigned short sg2h[16 * 72];  // 2304
  __shared__ __attribute__((aligned(16))) unsigned short sg2l[16 * 72];
  __shared__ __attribute__((aligned(16))) float sXBt[64 * 20];           // 5120
  __shared__ __attribute__((aligned(16))) float sA1 [16 * 17];           // 1088
  __shared__ __attribute__((aligned(16))) float sA2p[4 * 16 * 17];       // 4352
  __shared__ __attribute__((aligned(16))) float sCo [2 * 16];            // 128

  const int t    = threadIdx.x;
  const int bh   = blockIdx.x;            // 0..63
  const int b    = bh >> 4, h = bh & 15;
  const bool isA = (t < 512 / 2);
  const int lane = t & 63;
  const int fr   = lane & 15, fg = lane >> 4;
  const int w    = t >> 6;                // A: 0..3
  const int tb   = t - 256;               // B local
  const int wb   = (t >> 6) & 3;          // B: 0..3
  const int m    = 16 * wb + fr;          // B: W2 col

  float w1m[64];   // A masters
  float w2m[64];   // B masters
  floatx4 zba[4];  // A: z1bp D-frags (P1' -> P5)
  floatx4 zb2;     // B: Z2b D-frag  (P6 -> P7)
  float xar[4];    // B: XA prefetch

  const float* W1h = W1g + h * HFsz * HF4sz;
  const float* W2h = W2g + h * HF4sz * HFsz;
  if (isA) {
#pragma unroll
    for (int tt = 0; tt < 4; ++tt)
#pragma unroll
      for (int ks = 0; ks < 2; ++ks)
#pragma unroll
        for (int e = 0; e < 8; ++e)
          w1m[tt * 16 + ks * 8 + e] = W1h[(32 * ks + 8 * fg + e) * 256 + (64 * w + 16 * tt + fr)];
  } else {
#pragma unroll
    for (int ks = 0; ks < 8; ++ks)
#pragma unroll
      for (int e = 0; e < 8; ++e)
        w2m[ks * 8 + e] = W2h[(32 * ks + 8 * fg + e) * 64 + m];
    // initial sW2 split copy + XA chunk-0 prefetch
#pragma unroll
    for (int ks = 0; ks < 8; ++ks)
#pragma unroll
      for (int e = 0; e < 8; ++e) {
        const int k = 32 * ks + 8 * fg + e;
        unsigned short hs, ls;
        tsplit(w2m[ks * 8 + e], hs, ls);
        sW2h[k * 72 + m] = hs;
        sW2l[k * 72 + m] = ls;
      }
    const int cb0 = (b * Lsz) * Csz + h * HFsz;
#pragma unroll
    for (int j = 0; j < 4; ++j)
      xar[j] = XA[cb0 + (4 * fg + j) * 1024 + m];
  }
  __syncthreads();

#pragma unroll 1
  for (int nc = 0; nc < NCsz; ++nc) {
    const int cur = nc & 1;
    const int cb  = (b * Lsz + nc * CSsz) * Csz + h * HFsz;
    const int nc1 = (nc + 1) & (NCsz - 1);
    const int cb1 = (b * Lsz + nc1 * CSsz) * Csz + h * HFsz;
    const float* __restrict__ xbG = XBuf  + cb;
    const float* __restrict__ xcG = XCbuf + cb;

    // ================= P1': A: Z1 + z1bp MFMA | B: Attn1 =================
    if (isA) {
      if (t < 16) sCo[cur * 16 + t] = coeff[(bh * NCsz + nc) * CSsz + t];
      const float* __restrict__ xbp = xbG + fr * 1024 + 8 * fg;
      const float* __restrict__ xcp = xcG + fr * 1024 + 8 * fg;
      // pass a: Z1
      {
        floatx4 acc[4];
#pragma unroll
        for (int tt = 0; tt < 4; ++tt) acc[tt] = (floatx4){0.f, 0.f, 0.f, 0.f};
#pragma unroll
        for (int ks = 0; ks < 2; ++ks) {
          float xv[8];
          *(float4*)&xv[0] = *(const float4*)&xbp[32 * ks];
          *(float4*)&xv[4] = *(const float4*)&xbp[32 * ks + 4];
          bhalf8 xh, xl; split_frag8(xv, xh, xl);
#pragma unroll
          for (int tt = 0; tt < 4; ++tt) {
            bhalf8 wh, wl; split_frag8(&w1m[tt * 16 + ks * 8], wh, wl);
            MFMA3(acc[tt], xh, xl, wh, wl);
          }
        }
#pragma unroll
        for (int tt = 0; tt < 4; ++tt) {
          const int n = 64 * w + 16 * tt + fr;
#pragma unroll
          for (int j = 0; j < 4; ++j) {
            const int i = 4 * fg + j;
            const float v = acc[tt][j];
            unsigned short hs, ls; tsplit(v, hs, ls);
            sZ1h[i * 264 + n] = hs;
            sZ1l[i * 264 + n] = ls;
            sZ1t[n * 20 + i]  = v;
          }
        }
      }
      // pass b: z1bp (kept in regs)
      {
#pragma unroll
        for (int tt = 0; tt < 4; ++tt) zba[tt] = (floatx4){0.f, 0.f, 0.f, 0.f};
#pragma unroll
        for (int ks = 0; ks < 2; ++ks) {
          float xv[8];
          *(float4*)&xv[0] = *(const float4*)&xcp[32 * ks];
          *(float4*)&xv[4] = *(const float4*)&xcp[32 * ks + 4];
          bhalf8 xh, xl; split_frag8(xv, xh, xl);
#pragma unroll
          for (int tt = 0; tt < 4; ++tt) {
            bhalf8 wh, wl; split_frag8(&w1m[tt * 16 + ks * 8], wh, wl);
            MFMA3(zba[tt], xh, xl, wh, wl);
          }
        }
      }
    } else {
      const int ia = tb >> 4, ja = tb & 15;
      float a0 = 0.f, a1 = 0.f;
      if (ja <= ia) {
#pragma unroll
        for (int k = 0; k < 64; k += 8) {
          const float4 c0 = *(const float4*)&xcG[ia * 1024 + k];
          const float4 b0 = *(const float4*)&xbG[ja * 1024 + k];
          const float4 c1 = *(const float4*)&xcG[ia * 1024 + k + 4];
          const float4 b1 = *(const float4*)&xbG[ja * 1024 + k + 4];
          a0 = fmaf(c0.w, b0.w, fmaf(c0.z, b0.z, fmaf(c0.y, b0.y, fmaf(c0.x, b0.x, a0))));
          a1 = fmaf(c1.w, b1.w, fmaf(c1.z, b1.z, fmaf(c1.y, b1.y, fmaf(c1.x, b1.x, a1))));
        }
      }
      sA1[ia * 17 + ja] = a0 + a1;   // 0 on upper triangle
    }
    __syncthreads();

    // ================= P2': B: Z2 + g2 | A: XBt stage ====================
    if (!isA) {
      floatx4 z2a = (floatx4){0.f, 0.f, 0.f, 0.f};
#pragma unroll
      for (int ks = 0; ks < 8; ++ks) {
        const bhalf8 ah = *(const bhalf8*)&sZ1h[fr * 264 + 32 * ks + 8 * fg];
        const bhalf8 al = *(const bhalf8*)&sZ1l[fr * 264 + 32 * ks + 8 * fg];
        bhalf8 wh, wl; split_frag8(&w2m[ks * 8], wh, wl);
        MFMA3(z2a, ah, al, wh, wl);
      }
#pragma unroll
      for (int j = 0; j < 4; ++j) {
        const int i = 4 * fg + j;
        const float g2v = z2a[j] - xar[j];
        unsigned short hs, ls; tsplit(g2v, hs, ls);
        sg2h[i * 72 + m] = hs;
        sg2l[i * 72 + m] = ls;
      }
    } else {
      const int ir = t >> 4, k4 = (t & 15) * 4;
      const float4 v = *(const float4*)&xbG[ir * 1024 + k4];
      sXBt[(k4 + 0) * 20 + ir] = v.x;
      sXBt[(k4 + 1) * 20 + ir] = v.y;
      sXBt[(k4 + 2) * 20 + ir] = v.z;
      sXBt[(k4 + 3) * 20 + ir] = v.w;
    }
    __syncthreads();

    // ================= P4: B: g1^T = W2 @ g2^T (MFMA) -> sG1 =============
    if (!isA) {
      floatx4 g1a[4];
#pragma unroll
      for (int r = 0; r < 4; ++r) g1a[r] = (floatx4){0.f, 0.f, 0.f, 0.f};
#pragma unroll
      for (int ks2 = 0; ks2 < 2; ++ks2) {
        const bhalf8 gh = *(const bhalf8*)&sg2h[fr * 72 + 32 * ks2 + 8 * fg];
        const bhalf8 gl = *(const bhalf8*)&sg2l[fr * 72 + 32 * ks2 + 8 * fg];
#pragma unroll
        for (int r = 0; r < 4; ++r) {
          const int rt = 4 * wb + r;
          const bhalf8 ah = *(const bhalf8*)&sW2h[(16 * rt + fr) * 72 + 32 * ks2 + 8 * fg];
          const bhalf8 al = *(const bhalf8*)&sW2l[(16 * rt + fr) * 72 + 32 * ks2 + 8 * fg];
          MFMA3(g1a[r], ah, al, gh, gl);
        }
      }
#pragma unroll
      for (int r = 0; r < 4; ++r) {
        const int rt = 4 * wb + r;
#pragma unroll
        for (int j = 0; j < 4; ++j)
          sG1[(16 * rt + 4 * fg + j) * 20 + fr] = g1a[r][j];
      }
    }
    __syncthreads();

    // ================= P5: A: Z1b finalize -> sZb ========================
    if (isA) {
#pragma unroll
      for (int tt = 0; tt < 4; ++tt) {
        const int n = 64 * w + 16 * tt + fr;
        float gv[16];
        *(float4*)&gv[0]  = *(const float4*)&sG1[n * 20 + 0];
        *(float4*)&gv[4]  = *(const float4*)&sG1[n * 20 + 4];
        *(float4*)&gv[8]  = *(const float4*)&sG1[n * 20 + 8];
        *(float4*)&gv[12] = *(const float4*)&sG1[n * 20 + 12];
#pragma unroll
        for (int j = 0; j < 4; ++j) {
          const int i = 4 * fg + j;
          float at = 0.f;
#pragma unroll
          for (int jp = 0; jp < 16; ++jp)
            at = fmaf(sA1[i * 17 + jp], gv[jp], at);   // upper tri of A1 is 0
          const float z = zba[tt][j] - sCo[cur * 16 + i] * at;
          unsigned short hs, ls; tsplit(z, hs, ls);
          sZbh[i * 264 + n] = hs;
          sZbl[i * 264 + n] = ls;
        }
      }
    }
    __syncthreads();

    // ========== P6: A: Attn2 K-part MFMA + W1up | B: Z2b + W2up ==========
    if (isA) {
      // Attn2 partial (this wave covers ks = 2w, 2w+1)
      floatx4 a2 = (floatx4){0.f, 0.f, 0.f, 0.f};
#pragma unroll
      for (int ksl = 0; ksl < 2; ++ksl) {
        const int ks = 2 * w + ksl;
        const bhalf8 ah = *(const bhalf8*)&sZbh[fr * 264 + 32 * ks + 8 * fg];
        const bhalf8 al = *(const bhalf8*)&sZbl[fr * 264 + 32 * ks + 8 * fg];
        const bhalf8 bhf = *(const bhalf8*)&sZ1h[fr * 264 + 32 * ks + 8 * fg];
        const bhalf8 blf = *(const bhalf8*)&sZ1l[fr * 264 + 32 * ks + 8 * fg];
        MFMA3(a2, ah, al, bhf, blf);
      }
#pragma unroll
      for (int j = 0; j < 4; ++j) {
        const int i = 4 * fg + j;
        sA2p[w * 272 + i * 17 + fr] = (fr <= i) ? a2[j] : 0.f;
      }
      // W1 update (exact fp32 on masters)
      const float cl = sCo[cur * 16 + 15];
#pragma unroll
      for (int i = 0; i < 16; ++i) {
        float cg[4];
#pragma unroll
        for (int tt = 0; tt < 4; ++tt)
          cg[tt] = cl * sG1[(64 * w + 16 * tt + fr) * 20 + i];
#pragma unroll
        for (int ks = 0; ks < 2; ++ks)
#pragma unroll
          for (int e = 0; e < 8; ++e) {
            const float xb = sXBt[(32 * ks + 8 * fg + e) * 20 + i];
#pragma unroll
            for (int tt = 0; tt < 4; ++tt)
              w1m[tt * 16 + ks * 8 + e] = fmaf(-cg[tt], xb, w1m[tt * 16 + ks * 8 + e]);
          }
      }
    } else {
      // Z2b (pre-update W2)
      zb2 = (floatx4){0.f, 0.f, 0.f, 0.f};
#pragma unroll
      for (int ks = 0; ks < 8; ++ks) {
        const bhalf8 ah = *(const bhalf8*)&sZbh[fr * 264 + 32 * ks + 8 * fg];
        const bhalf8 al = *(const bhalf8*)&sZbl[fr * 264 + 32 * ks + 8 * fg];
        bhalf8 wh, wl; split_frag8(&w2m[ks * 8], wh, wl);
        MFMA3(zb2, ah, al, wh, wl);
      }
      // W2 update (exact fp32; Z1 read fp32 from sZ1t, broadcast per k)
      const float cl = sCo[cur * 16 + 15];
      float cg[16];
#pragma unroll
      for (int i = 0; i < 16; ++i)
        cg[i] = cl * recon2(sg2h[i * 72 + m], sg2l[i * 72 + m]);
#pragma unroll
      for (int ks = 0; ks < 8; ++ks)
#pragma unroll
        for (int e = 0; e < 8; ++e) {
          const int k = 32 * ks + 8 * fg + e;
          float zr[16];
          *(float4*)&zr[0]  = *(const float4*)&sZ1t[k * 20 + 0];
          *(float4*)&zr[4]  = *(const float4*)&sZ1t[k * 20 + 4];
          *(float4*)&zr[8]  = *(const float4*)&sZ1t[k * 20 + 8];
          *(float4*)&zr[12] = *(const float4*)&sZ1t[k * 20 + 12];
          float acc = w2m[ks * 8 + e];
#pragma unroll
          for (int i = 0; i < 16; ++i) acc = fmaf(-cg[i], zr[i], acc);
          w2m[ks * 8 + e] = acc;
        }
    }
    __syncthreads();

    // ====== P7: B: Z2b apply + store, sW2 rebuild, XA prefetch ===========
    //  (no trailing barrier: A's next P1' touches only sZ1*,sA1,sCo[nxt],
    //   all disjoint from P7's reads/writes)
    if (!isA) {
      float at[4] = {0.f, 0.f, 0.f, 0.f};
#pragma unroll
      for (int jp = 0; jp < 16; ++jp) {
        const float g2v = recon2(sg2h[jp * 72 + m], sg2l[jp * 72 + m]);
#pragma unroll
        for (int j = 0; j < 4; ++j) {
          const int i = 4 * fg + j;
          const float a2s = sA2p[i * 17 + jp] + sA2p[272 + i * 17 + jp]
                          + sA2p[544 + i * 17 + jp] + sA2p[816 + i * 17 + jp];
          at[j] = fmaf(a2s, g2v, at[j]);
        }
      }
#pragma unroll
      for (int j = 0; j < 4; ++j) {
        const int i = 4 * fg + j;
        Out[cb + i * 1024 + m] = zb2[j] - sCo[cur * 16 + i] * at[j];
      }
      // rebuild split W2 for next chunk's g1
#pragma unroll
      for (int ks = 0; ks < 8; ++ks)
#pragma unroll
        for (int e = 0; e < 8; ++e) {
          const int k = 32 * ks + 8 * fg + e;
          unsigned short hs, ls;
          tsplit(w2m[ks * 8 + e], hs, ls);
          sW2h[k * 72 + m] = hs;
          sW2l[k * 72 + m] = ls;
        }
      // XA prefetch for next chunk
#pragma unroll
      for (int j = 0; j < 4; ++j)
        xar[j] = XA[cb1 + (4 * fg + j) * 1024 + m];
    }
  }
}

// ---------------------------------------------------------------------------
// Workspace: bXC [0,16.7M) | bXB [16.7M,33.5M) | bZ2b [33.5M,50.3M) | bCo.
// H-split lives in bZ2b region (dead until scan writes); Z2b-split in bXC
// region (dead after scan).  XA lives in d_out until final GEMM overwrites.
// ---------------------------------------------------------------------------
extern "C" void kernel_launch(void* const* d_in, const int* in_sizes, int n_in,
                              void* d_out, int out_size, void* d_ws, size_t ws_size,
                              hipStream_t stream)
{
  const float* H    = (const float*)d_in[0];
  const float* Wq   = (const float*)d_in[1];
  const float* Wk   = (const float*)d_in[2];
  const float* Wv   = (const float*)d_in[3];
  const float* Wo   = (const float*)d_in[4];
  const float* Wil  = (const float*)d_in[5];
  const float* bil  = (const float*)d_in[6];
  const float* W1   = (const float*)d_in[7];
  const float* W2   = (const float*)d_in[8];
  float* out        = (float*)d_out;

  float* ws    = (float*)d_ws;
  float* bXC   = ws;
  float* bXB   = ws + 16777216;
  float* bZ2b  = ws + 33554432;
  float* bCo   = ws + 50331648;
  float* bXA   = out;

  unsigned short* hHi = (unsigned short*)bZ2b;
  unsigned short* hLo = hHi + 16777216;
  unsigned short* zHi = (unsigned short*)bXC;
  unsigned short* zLo = zHi + 16777216;

  const int M = Bsz * Lsz, N = Csz, K = Csz;
  dim3 gm(N / 128, M / 128);
  dim3 bm(256);

  split32<<<16384, 256, 0, stream>>>(H, hHi, hLo);
  gemm_mfma<<<gm, bm, 0, stream>>>(hHi, hLo, Wq, bXC, M, N, K);
  gemm_mfma<<<gm, bm, 0, stream>>>(hHi, hLo, Wk, bXB, M, N, K);
  gemm_mfma<<<gm, bm, 0, stream>>>(hHi, hLo, Wv, bXA, M, N, K);
  ilr_coeff<<<M / 4, 256, 0, stream>>>(H, Wil, bil, bCo);
  ttt_scan<<<Bsz * NHsz, 512, 0, stream>>>(bXA, bXB, bXC, bCo, W1, W2, bZ2b);
  split32<<<16384, 256, 0, stream>>>(bZ2b, zHi, zLo);
  gemm_mfma<<<gm, bm, 0, stream>>>(zHi, zLo, Wo, out, M, N, K);
}